// Round 4
// baseline (578.362 us; speedup 1.0000x reference)
//
#include <hip/hip_runtime.h>
#include <hip/hip_bf16.h>
#include <math.h>

// B=2,H=16 (BH=32), T=2048, D=64. fp32 in/out.
// d_out = [out (BH*T*64) | attn (BH*T*T)] fp32.
//
// R4: swapped-operand QK^T (lane owns one q-row, 4 consecutive s per reg) ->
// float4 attn stores + b64 P-LDS writes; PV before attn stores (flash-style,
// unnormalized P, single barrier, stores dead-last); 256-thread blocks with
// BM=16 -> 2 blocks/CU; P_lo dropped in PV (error ~2e-4, budget 6.5e-3).

#define T_SEQ  2048
#define D_HEAD 64
#define BH_N   32
#define BMR    16            // q rows per block
#define WV     4             // waves per block
#define WC     512           // score columns per wave
#define OUT_ELEMS (BH_N * T_SEQ * D_HEAD)

typedef __attribute__((ext_vector_type(8))) short bf16x8;
typedef __attribute__((ext_vector_type(4))) float f32x4;

__device__ __forceinline__ unsigned short f2bf(float x) {
    __hip_bfloat16 h = __float2bfloat16(x);
    return *reinterpret_cast<unsigned short*>(&h);
}
__device__ __forceinline__ float bf2f(unsigned short u) {
    __hip_bfloat16 h;
    *reinterpret_cast<unsigned short*>(&h) = u;
    return __bfloat162float(h);
}

// ---------------- precompute: rope tables ----------------
__global__ void rope_table_kernel(float* __restrict__ ctab, float* __restrict__ stab) {
    int i = blockIdx.x * blockDim.x + threadIdx.x;
    if (i >= T_SEQ * 32) return;
    int t = i >> 5;
    int j = i & 31;
    float invf = powf(10000.0f, -(float)j / 32.0f);
    float a = (float)t * invf;
    ctab[i] = cosf(a);
    stab[i] = sinf(a);
}

// ---------------- precompute: rope + hi/lo split for Q,K ----------------
__global__ __launch_bounds__(256)
void ropesplit_kernel(const float* __restrict__ X, const float* __restrict__ ctab,
                      const float* __restrict__ stab, unsigned short* __restrict__ H,
                      unsigned short* __restrict__ L, float scale)
{
    const int r  = blockIdx.x * 16 + (threadIdx.x >> 4);   // global row in [0, BH*T)
    const int c4 = threadIdx.x & 15;
    const int t  = r & (T_SEQ - 1);
    const float4* xr = (const float4*)(X + (size_t)r * 64);
    float4 a = xr[c4];
    float4 b = xr[c4 ^ 8];
    float4 c = ((const float4*)(ctab + t * 32))[c4 & 7];
    float4 s = ((const float4*)(stab + t * 32))[c4 & 7];
    float4 ro;
    if (c4 < 8) {
        ro.x = a.x * c.x - b.x * s.x; ro.y = a.y * c.y - b.y * s.y;
        ro.z = a.z * c.z - b.z * s.z; ro.w = a.w * c.w - b.w * s.w;
    } else {
        ro.x = a.x * c.x + b.x * s.x; ro.y = a.y * c.y + b.y * s.y;
        ro.z = a.z * c.z + b.z * s.z; ro.w = a.w * c.w + b.w * s.w;
    }
    ro.x *= scale; ro.y *= scale; ro.z *= scale; ro.w *= scale;
    ushort4 h, l;
    h.x = f2bf(ro.x); l.x = f2bf(ro.x - bf2f(h.x));
    h.y = f2bf(ro.y); l.y = f2bf(ro.y - bf2f(h.y));
    h.z = f2bf(ro.z); l.z = f2bf(ro.z - bf2f(h.z));
    h.w = f2bf(ro.w); l.w = f2bf(ro.w - bf2f(h.w));
    *(ushort4*)(H + (size_t)r * 64 + c4 * 4) = h;
    *(ushort4*)(L + (size_t)r * 64 + c4 * 4) = l;
}

// ---------------- precompute: V transpose + hi/lo split ----------------
__global__ __launch_bounds__(256)
void vtrans_kernel(const float* __restrict__ V, unsigned short* __restrict__ Vth,
                   unsigned short* __restrict__ Vtl)
{
    __shared__ float tile[64][65];
    const int bh = blockIdx.y;
    const int tt = blockIdx.x;            // 64-row t-tile
    const float* vg = V + ((size_t)bh * T_SEQ + tt * 64) * 64;
    #pragma unroll
    for (int i = 0; i < 4; ++i) {
        const int row = (threadIdx.x >> 4) + i * 16;
        const int c4  = threadIdx.x & 15;
        float4 a = *(const float4*)(vg + (size_t)row * 64 + c4 * 4);
        tile[row][c4 * 4 + 0] = a.x; tile[row][c4 * 4 + 1] = a.y;
        tile[row][c4 * 4 + 2] = a.z; tile[row][c4 * 4 + 3] = a.w;
    }
    __syncthreads();
    #pragma unroll
    for (int i = 0; i < 4; ++i) {
        const int d   = (threadIdx.x >> 4) + i * 16;
        const int tc4 = threadIdx.x & 15;
        ushort4 h, l;
        float x0 = tile[tc4 * 4 + 0][d];
        float x1 = tile[tc4 * 4 + 1][d];
        float x2 = tile[tc4 * 4 + 2][d];
        float x3 = tile[tc4 * 4 + 3][d];
        h.x = f2bf(x0); l.x = f2bf(x0 - bf2f(h.x));
        h.y = f2bf(x1); l.y = f2bf(x1 - bf2f(h.y));
        h.z = f2bf(x2); l.z = f2bf(x2 - bf2f(h.z));
        h.w = f2bf(x3); l.w = f2bf(x3 - bf2f(h.w));
        size_t off = ((size_t)bh * 64 + d) * T_SEQ + tt * 64 + tc4 * 4;
        *(ushort4*)(Vth + off) = h;
        *(ushort4*)(Vtl + off) = l;
    }
}

// ---------------- main attention kernel ----------------
__global__ __launch_bounds__(256, 2)
void attn_mfma_kernel(const unsigned short* __restrict__ Qh, const unsigned short* __restrict__ Ql,
                      const unsigned short* __restrict__ Kh, const unsigned short* __restrict__ Kl,
                      const unsigned short* __restrict__ Vth, const unsigned short* __restrict__ Vtl,
                      float* __restrict__ out, float* __restrict__ attn)
{
    __shared__ float rsum[WV][16];
    __shared__ __align__(16) unsigned short pbuf[WV][16][72];  // 9216 B, stride 144B (16B-aligned rows)
    __shared__ __align__(16) float pout[WV][16][76];           // 19456 B, stride 304B

    const int tid  = threadIdx.x;
    const int lane = tid & 63;
    const int w    = tid >> 6;
    const int lrow = lane & 15;     // q-row within block
    const int lgrp = lane >> 4;

    // XCD-aware bijective swizzle: 4096 blocks, 4096%8==0
    const int lid = blockIdx.x;
    const int vid = (lid & 7) * 512 + (lid >> 3);
    const int bh  = vid >> 7;
    const int m   = vid & 127;
    const int t0  = m * BMR;
    const int c0  = w * WC;

    const size_t base = (size_t)bh * T_SEQ * D_HEAD;
    const unsigned short* qh  = Qh  + base + (size_t)t0 * D_HEAD;
    const unsigned short* ql  = Ql  + base + (size_t)t0 * D_HEAD;
    const unsigned short* kh  = Kh  + base;
    const unsigned short* kl  = Kl  + base;
    const unsigned short* vth = Vth + base;   // layout [bh][64][T]
    const unsigned short* vtl = Vtl + base;

    // --- Q fragments as B-operand: col = lane&15 = q-row, k-slice = lgrp*8 ---
    bf16x8 qfh[2], qfl[2];
    #pragma unroll
    for (int ks = 0; ks < 2; ++ks) {
        const int off = lrow * 64 + ks * 32 + lgrp * 8;
        qfh[ks] = *(const bf16x8*)(qh + off);
        qfl[ks] = *(const bf16x8*)(ql + off);
    }

    // --- S^T = K·Q^T (compensated): lane holds q=lrow, s = nt*16 + lgrp*4 + j ---
    f32x4 s[32];
    #pragma unroll
    for (int nt = 0; nt < 32; ++nt) s[nt] = (f32x4){0.f, 0.f, 0.f, 0.f};

    #pragma unroll
    for (int nt = 0; nt < 32; ++nt) {
        const int coff = (c0 + nt * 16 + lrow) * 64 + lgrp * 8;
        bf16x8 k_h0 = *(const bf16x8*)(kh + coff);
        bf16x8 k_h1 = *(const bf16x8*)(kh + coff + 32);
        bf16x8 k_l0 = *(const bf16x8*)(kl + coff);
        bf16x8 k_l1 = *(const bf16x8*)(kl + coff + 32);
        f32x4 acc = s[nt];
        acc = __builtin_amdgcn_mfma_f32_16x16x32_bf16(k_h0, qfh[0], acc, 0, 0, 0);
        acc = __builtin_amdgcn_mfma_f32_16x16x32_bf16(k_h1, qfh[1], acc, 0, 0, 0);
        acc = __builtin_amdgcn_mfma_f32_16x16x32_bf16(k_h0, qfl[0], acc, 0, 0, 0);
        acc = __builtin_amdgcn_mfma_f32_16x16x32_bf16(k_h1, qfl[1], acc, 0, 0, 0);
        acc = __builtin_amdgcn_mfma_f32_16x16x32_bf16(k_l0, qfh[0], acc, 0, 0, 0);
        acc = __builtin_amdgcn_mfma_f32_16x16x32_bf16(k_l1, qfh[1], acc, 0, 0, 0);
        s[nt] = acc;
    }

    // --- exp (no max subtraction: scores bounded, exp safe in fp32) ---
    #pragma unroll
    for (int nt = 0; nt < 32; ++nt)
        #pragma unroll
        for (int j = 0; j < 4; ++j)
            s[nt][j] = __expf(s[nt][j]);

    // --- row sum for q=lrow: in-lane partial + reduce over lgrp (xor 16,32) ---
    {
        float rp = 0.f;
        #pragma unroll
        for (int nt = 0; nt < 32; ++nt)
            rp += s[nt][0] + s[nt][1] + s[nt][2] + s[nt][3];
        rp += __shfl_xor(rp, 16, 64);
        rp += __shfl_xor(rp, 32, 64);
        if (lane < 16) rsum[w][lrow] = rp;
    }

    // --- PV with unnormalized P (hi only; V hi+lo) ---
    f32x4 o[4];
    #pragma unroll
    for (int nd = 0; nd < 4; ++nd) o[nd] = (f32x4){0.f, 0.f, 0.f, 0.f};

    unsigned short* pb = &pbuf[w][0][0];
    #pragma unroll
    for (int cc = 0; cc < 8; ++cc) {
        #pragma unroll
        for (int ntl = 0; ntl < 4; ++ntl) {
            const int nt = cc * 4 + ntl;
            ushort4 p4;
            p4.x = f2bf(s[nt][0]); p4.y = f2bf(s[nt][1]);
            p4.z = f2bf(s[nt][2]); p4.w = f2bf(s[nt][3]);
            *(ushort4*)(pb + lrow * 72 + ntl * 16 + lgrp * 4) = p4;
        }
        asm volatile("s_waitcnt lgkmcnt(0)" ::: "memory");
        __builtin_amdgcn_sched_barrier(0);
        #pragma unroll
        for (int ks2 = 0; ks2 < 2; ++ks2) {
            bf16x8 pa = *(const bf16x8*)(pb + lrow * 72 + ks2 * 32 + lgrp * 8);
            #pragma unroll
            for (int nd = 0; nd < 4; ++nd) {
                const size_t voff = (size_t)(nd * 16 + lrow) * T_SEQ + c0 + cc * 64 + ks2 * 32 + lgrp * 8;
                bf16x8 vh = *(const bf16x8*)(vth + voff);
                bf16x8 vl = *(const bf16x8*)(vtl + voff);
                f32x4 a = o[nd];
                a = __builtin_amdgcn_mfma_f32_16x16x32_bf16(pa, vh, a, 0, 0, 0);
                a = __builtin_amdgcn_mfma_f32_16x16x32_bf16(pa, vl, a, 0, 0, 0);
                o[nd] = a;
            }
        }
    }

    // --- cross-wave out reduction (pout separate from pbuf; single barrier) ---
    #pragma unroll
    for (int nd = 0; nd < 4; ++nd)
        #pragma unroll
        for (int j = 0; j < 4; ++j)
            pout[w][lgrp * 4 + j][nd * 16 + lrow] = o[nd][j];
    __syncthreads();

    // per-lane inverse row sum for q = lrow (stable after barrier)
    const float inv = 1.0f / (rsum[0][lrow] + rsum[1][lrow] + rsum[2][lrow] + rsum[3][lrow]);

    {
        const int r  = tid >> 4;          // 0..15
        const int c4 = tid & 15;
        f32x4 a = (f32x4){0.f, 0.f, 0.f, 0.f};
        #pragma unroll
        for (int ww = 0; ww < WV; ++ww) {
            const f32x4 p = *(const f32x4*)&pout[ww][r][c4 * 4];
            a.x += p.x; a.y += p.y; a.z += p.z; a.w += p.w;
        }
        const float invr = 1.0f / (rsum[0][r] + rsum[1][r] + rsum[2][r] + rsum[3][r]);
        a.x *= invr; a.y *= invr; a.z *= invr; a.w *= invr;
        f32x4* og = (f32x4*)(out + base + (size_t)(t0 + r) * D_HEAD + c4 * 4);
        __builtin_nontemporal_store(a, og);
    }

    // --- attn normalize + store (dead-last: no vmem reads after) ---
    float* arow = attn + (size_t)bh * T_SEQ * T_SEQ + (size_t)(t0 + lrow) * T_SEQ + c0 + lgrp * 4;
    #pragma unroll
    for (int nt = 0; nt < 32; ++nt) {
        f32x4 av;
        av.x = s[nt][0] * inv; av.y = s[nt][1] * inv;
        av.z = s[nt][2] * inv; av.w = s[nt][3] * inv;
        __builtin_nontemporal_store(av, (f32x4*)(arow + nt * 16));
    }
}

extern "C" void kernel_launch(void* const* d_in, const int* in_sizes, int n_in,
                              void* d_out, int out_size, void* d_ws, size_t ws_size,
                              hipStream_t stream) {
    const float* q = (const float*)d_in[0];
    const float* k = (const float*)d_in[1];
    const float* v = (const float*)d_in[2];
    float* out  = (float*)d_out;
    float* attn = out + (size_t)OUT_ELEMS;

    // d_ws layout
    float* ctab = (float*)d_ws;                                  // T*32 f32
    float* stab = ctab + T_SEQ * 32;                             // T*32 f32
    unsigned short* wsu = (unsigned short*)(stab + T_SEQ * 32);
    const size_t NE = (size_t)BH_N * T_SEQ * D_HEAD;             // 4,194,304
    unsigned short* Qh  = wsu + 0 * NE;
    unsigned short* Ql  = wsu + 1 * NE;
    unsigned short* Kh  = wsu + 2 * NE;
    unsigned short* Kl  = wsu + 3 * NE;
    unsigned short* Vth = wsu + 4 * NE;
    unsigned short* Vtl = wsu + 5 * NE;                          // total ws ~48.5 MB

    rope_table_kernel<<<dim3((T_SEQ * 32 + 255) / 256), dim3(256), 0, stream>>>(ctab, stab);
    ropesplit_kernel<<<dim3(BH_N * T_SEQ / 16), dim3(256), 0, stream>>>(q, ctab, stab, Qh, Ql, 0.125f);
    ropesplit_kernel<<<dim3(BH_N * T_SEQ / 16), dim3(256), 0, stream>>>(k, ctab, stab, Kh, Kl, 1.0f);
    vtrans_kernel<<<dim3(T_SEQ / 64, BH_N), dim3(256), 0, stream>>>(v, Vth, Vtl);
    attn_mfma_kernel<<<dim3(BH_N * T_SEQ / BMR), dim3(256), 0, stream>>>(Qh, Ql, Kh, Kl, Vth, Vtl, out, attn);
}